// Round 4
// baseline (153.584 us; speedup 1.0000x reference)
//
#include <hip/hip_runtime.h>
#include <math.h>

#define N_RAY 65536
#define KPTS 256
#define NXV 256
#define NYV 256
#define NZV 256

typedef float f4vec __attribute__((ext_vector_type(4)));

// One wave (64 lanes) per ray; lane l owns the 4 contiguous segments 4l..4l+3.
//
// Key structure (R4): the volume row address depends only on (sx,sy), NOT on
// t. So the wave issues the coalesced row load (one float4/lane = the whole
// 1KB row, each 64B line fetched exactly once) IN PARALLEL with the t float4
// load, then stages the row in its private LDS slice and gathers from LDS.
// This removes the serial t->gather global-latency chain and cuts volume
// L1->L2 line traffic 4x vs per-lane scattered gathers. t_sorted is pure
// streaming (no reuse) -> nontemporal loads keep it from evicting volume
// rows out of L2.
//
// Fast path validity (bit-exact vs reference, as established R2/R3):
//   M == I bitwise && b == 0  -> cofactor inverse is exactly I
//   dx == dy == 0             -> p0x=sx, mid_x=sx, ii=rint(sx) for all segs
//   seg = sqrt(rn(ez^2)) == |ez| (IEEE rn identity)
// Accumulation order identical to R3 (per-lane fma over 4 segs, 64-lane
// butterfly), so output is bit-identical to the passing R3 kernel.
__global__ __launch_bounds__(256) void ct_proj_kernel(
    const float* __restrict__ volume,
    const float* __restrict__ Mmat,
    const float* __restrict__ bvec,
    const float* __restrict__ src,
    const float* __restrict__ dst,
    const float* __restrict__ t_sorted,
    float* __restrict__ out)
{
    __shared__ float rowbuf[4][NZV];   // 1KB per wave, 4KB per block

    const int lane = threadIdx.x & 63;
    const int wid  = threadIdx.x >> 6;
    const int ray  = __builtin_amdgcn_readfirstlane(blockIdx.x * 4 + wid);

    const float bx = bvec[0], by = bvec[1], bz = bvec[2];

    const float sx = src[3 * ray + 0];
    const float sy = src[3 * ray + 1];
    const float sz = src[3 * ray + 2];
    const float dx = __fsub_rn(dst[3 * ray + 0], sx);
    const float dy = __fsub_rn(dst[3 * ray + 1], sy);
    const float dz = __fsub_rn(dst[3 * ray + 2], sz);

    const float* t = t_sorted + (size_t)ray * KPTS;

    const bool fastM =
        (Mmat[0] == 1.0f) && (Mmat[1] == 0.0f) && (Mmat[2] == 0.0f) &&
        (Mmat[3] == 0.0f) && (Mmat[4] == 1.0f) && (Mmat[5] == 0.0f) &&
        (Mmat[6] == 0.0f) && (Mmat[7] == 0.0f) && (Mmat[8] == 1.0f) &&
        (bx == 0.0f) && (by == 0.0f) && (bz == 0.0f);
    const bool fastR = fastM && (dx == 0.0f) && (dy == 0.0f) &&
                       isfinite(sx) && isfinite(sy) && isfinite(sz) &&
                       isfinite(dz);

    float acc = 0.0f;

    if (fastR) {
        // ---------------- fast path ----------------
        const int ii = (int)rintf(sx);   // == rint(mid_x) exactly
        const int jj = (int)rintf(sy);
        if ((unsigned)ii < NXV && (unsigned)jj < NYV) {
            const unsigned rowoff = __builtin_amdgcn_readfirstlane(
                ((unsigned)ii * NYV + (unsigned)jj) * NZV);

            // Independent loads, issued back to back:
            //   row: coalesced float4/lane (whole 1KB row, temporal -> L2)
            //   t:   coalesced float4/lane (streaming -> nontemporal)
            const f4vec rv = *reinterpret_cast<const f4vec*>(
                volume + rowoff + 4 * lane);
            const f4vec tv = __builtin_nontemporal_load(
                reinterpret_cast<const f4vec*>(t + 4 * lane));

            // stage row into this wave's private LDS slice (no barrier:
            // same wave produces and consumes; hw waits via lgkmcnt)
            float* __restrict__ buf = rowbuf[wid];
            *reinterpret_cast<f4vec*>(buf + 4 * lane) = rv;

            const float t4 = __shfl_down(tv.x, 1, 64);  // t[4(l+1)]

            // 5 shared point evals (mul-then-add, rn — matches reference)
            const float p0 = __fadd_rn(sz, __fmul_rn(tv.x, dz));
            const float p1 = __fadd_rn(sz, __fmul_rn(tv.y, dz));
            const float p2 = __fadd_rn(sz, __fmul_rn(tv.z, dz));
            const float p3 = __fadd_rn(sz, __fmul_rn(tv.w, dz));
            const float p4 = __fadd_rn(sz, __fmul_rn(t4,   dz));

            const bool f0 = !isinf(p0), f1 = !isinf(p1), f2 = !isinf(p2),
                       f3 = !isinf(p3), f4 = !isinf(p4);

            {   // seg 4l+0
                const float ez   = __fsub_rn(p1, p0);
                const float midz = __fmul_rn(0.5f, __fadd_rn(p0, p1));
                const int   kk   = (int)rintf(midz);
                const bool  v    = ((unsigned)kk < NZV) && f0 && f1;
                acc = fmaf(buf[v ? kk : 0], v ? fabsf(ez) : 0.0f, acc);
            }
            {   // seg 4l+1
                const float ez   = __fsub_rn(p2, p1);
                const float midz = __fmul_rn(0.5f, __fadd_rn(p1, p2));
                const int   kk   = (int)rintf(midz);
                const bool  v    = ((unsigned)kk < NZV) && f1 && f2;
                acc = fmaf(buf[v ? kk : 0], v ? fabsf(ez) : 0.0f, acc);
            }
            {   // seg 4l+2
                const float ez   = __fsub_rn(p3, p2);
                const float midz = __fmul_rn(0.5f, __fadd_rn(p2, p3));
                const int   kk   = (int)rintf(midz);
                const bool  v    = ((unsigned)kk < NZV) && f2 && f3;
                acc = fmaf(buf[v ? kk : 0], v ? fabsf(ez) : 0.0f, acc);
            }
            {   // seg 4l+3 (lane 63's is segment 255 -> masked)
                const float ez   = __fsub_rn(p4, p3);
                const float midz = __fmul_rn(0.5f, __fadd_rn(p3, p4));
                const int   kk   = (int)rintf(midz);
                const bool  v    = ((unsigned)kk < NZV) && f3 && f4 &&
                                   (lane != 63);
                acc = fmaf(buf[v ? kk : 0], v ? fabsf(ez) : 0.0f, acc);
            }
        }
        // else: whole ray OOB in x/y -> sum is 0
    } else {
        // ---------------- general path (reference-exact cofactor inverse) ----
        const float m00 = Mmat[0], m01 = Mmat[1], m02 = Mmat[2];
        const float m10 = Mmat[3], m11 = Mmat[4], m12 = Mmat[5];
        const float m20 = Mmat[6], m21 = Mmat[7], m22 = Mmat[8];
        const float c00 =  (m11 * m22 - m12 * m21);
        const float c01 = -(m10 * m22 - m12 * m20);
        const float c02 =  (m10 * m21 - m11 * m20);
        const float det = m00 * c00 + m01 * c01 + m02 * c02;
        const float id  = 1.0f / det;
        const float i00 = c00 * id;
        const float i01 = -(m01 * m22 - m02 * m21) * id;
        const float i02 =  (m01 * m12 - m02 * m11) * id;
        const float i10 = c01 * id;
        const float i11 =  (m00 * m22 - m02 * m20) * id;
        const float i12 = -(m00 * m12 - m02 * m10) * id;
        const float i20 = c02 * id;
        const float i21 = -(m00 * m21 - m01 * m20) * id;
        const float i22 =  (m00 * m11 - m01 * m10) * id;

        #pragma unroll
        for (int it = 0; it < 4; ++it) {
            const int idx = it * 64 + lane;
            if (idx < KPTS - 1) {
                const float tkv  = t[idx];
                const float tk1v = t[idx + 1];
                const float p0x = __fadd_rn(sx, __fmul_rn(tkv,  dx));
                const float p0y = __fadd_rn(sy, __fmul_rn(tkv,  dy));
                const float p0z = __fadd_rn(sz, __fmul_rn(tkv,  dz));
                const float p1x = __fadd_rn(sx, __fmul_rn(tk1v, dx));
                const float p1y = __fadd_rn(sy, __fmul_rn(tk1v, dy));
                const float p1z = __fadd_rn(sz, __fmul_rn(tk1v, dz));

                const bool infm = isinf(p0x) || isinf(p0y) || isinf(p0z) ||
                                  isinf(p1x) || isinf(p1y) || isinf(p1z);

                const float ex = __fsub_rn(p1x, p0x);
                const float ey = __fsub_rn(p1y, p0y);
                const float ez = __fsub_rn(p1z, p0z);
                const float seg = sqrtf(ex * ex + ey * ey + ez * ez);

                const float mx = __fsub_rn(__fmul_rn(0.5f, __fadd_rn(p0x, p1x)), bx);
                const float my = __fsub_rn(__fmul_rn(0.5f, __fadd_rn(p0y, p1y)), by);
                const float mz = __fsub_rn(__fmul_rn(0.5f, __fadd_rn(p0z, p1z)), bz);

                const float fi = __fadd_rn(__fadd_rn(__fmul_rn(i00, mx), __fmul_rn(i01, my)), __fmul_rn(i02, mz));
                const float fj = __fadd_rn(__fadd_rn(__fmul_rn(i10, mx), __fmul_rn(i11, my)), __fmul_rn(i12, mz));
                const float fk = __fadd_rn(__fadd_rn(__fmul_rn(i20, mx), __fmul_rn(i21, my)), __fmul_rn(i22, mz));

                const int ii = (int)rintf(fi);
                const int jj = (int)rintf(fj);
                const int kk = (int)rintf(fk);

                const bool oob = (ii < 0) || (ii >= NXV) ||
                                 (jj < 0) || (jj >= NYV) ||
                                 (kk < 0) || (kk >= NZV);

                if (!infm && !oob) {
                    const float vox = volume[((size_t)ii * NYV + jj) * NZV + kk];
                    acc = fmaf(vox, seg, acc);
                }
            }
        }
    }

    // wave-wide sum (64 lanes)
    #pragma unroll
    for (int off = 32; off >= 1; off >>= 1)
        acc += __shfl_xor(acc, off, 64);

    if (lane == 0) out[ray] = acc;
}

extern "C" void kernel_launch(void* const* d_in, const int* in_sizes, int n_in,
                              void* d_out, int out_size, void* d_ws, size_t ws_size,
                              hipStream_t stream) {
    const float* volume   = (const float*)d_in[0];
    const float* Mmat     = (const float*)d_in[1];
    const float* bvec     = (const float*)d_in[2];
    const float* src      = (const float*)d_in[3];
    const float* dst      = (const float*)d_in[4];
    const float* t_sorted = (const float*)d_in[5];
    float* out = (float*)d_out;

    const int rays_per_block = 4;                 // 4 waves x 64 lanes
    const int grid = N_RAY / rays_per_block;      // 16384 blocks
    ct_proj_kernel<<<grid, 256, 0, stream>>>(volume, Mmat, bvec, src, dst,
                                             t_sorted, out);
}

// Round 5
// 152.497 us; speedup vs baseline: 1.0071x; 1.0071x over previous
//
#include <hip/hip_runtime.h>
#include <math.h>

#define N_RAY 65536
#define KPTS 256
#define NXV 256
#define NYV 256
#define NZV 256
#define RPW 8   // rays per wave

typedef float f4vec __attribute__((ext_vector_type(4)));

// 8 rays per wave, software-pipelined:
//   - src/dst for all 8 rays fetched cooperatively (24 contiguous floats
//     each, one coalesced load), distributed via __shfl -> classify once,
//     row offsets held in SGPRs (readfirstlane), fast/inbounds bitmasks.
//   - t float4 loads issued 4 rays ahead (nontemporal streaming),
//     volume-row loads 3 rays ahead, row->LDS write 1 ray ahead into a
//     double-buffered per-wave slice. The per-wave serial chain
//     (src -> classify -> row) is paid ONCE per 8 rays instead of per ray.
//   - LDS layout de-interleaved: row element e lives at (e&3)*64 + (e>>2).
//     Writes are 4x ds_write_b32 stride-1 (conflict-free); gathers with
//     kk ~ 4*lane+c map to bank ~ lane (conflict-free for sorted-t rays).
//
// Per-ray math identical to the R3/R4 kernels (bit-exact vs reference on
// the fast path: M==I bitwise, b==0, dx==dy==0 => ii=rint(sx), jj=rint(sy),
// seg=|ez|; same fma accumulation order + 64-lane butterfly).
__global__ __launch_bounds__(256, 4) void ct_proj_kernel(
    const float* __restrict__ volume,
    const float* __restrict__ Mmat,
    const float* __restrict__ bvec,
    const float* __restrict__ src,
    const float* __restrict__ dst,
    const float* __restrict__ t_sorted,
    float* __restrict__ out)
{
    __shared__ float rowbuf[4][2][NZV];   // 2-slice double buffer per wave

    const int lane = threadIdx.x & 63;
    const int wid  = threadIdx.x >> 6;
    const int wave = blockIdx.x * 4 + wid;
    const int ray0 = wave * RPW;

    float (* __restrict__ slice)[NZV] = rowbuf[wid];

    // ---- cooperative src/dst fetch (24 floats per array for 8 rays) ----
    const int sdi = lane < 24 ? lane : 23;
    const float sv = src[3 * ray0 + sdi];
    const float dv = dst[3 * ray0 + sdi];

    // ---- t prefetch: first 4 rays (independent of src/dst) ----
    const float* tbase = t_sorted + (size_t)ray0 * KPTS;
    f4vec tvv[RPW];
    #pragma unroll
    for (int i = 0; i < 4; ++i)
        tvv[i] = __builtin_nontemporal_load(
            reinterpret_cast<const f4vec*>(tbase + i * KPTS + 4 * lane));

    // ---- wave-uniform M / b identity check ----
    const float bx = bvec[0], by = bvec[1], bz = bvec[2];
    const bool fastM =
        (Mmat[0] == 1.0f) && (Mmat[1] == 0.0f) && (Mmat[2] == 0.0f) &&
        (Mmat[3] == 0.0f) && (Mmat[4] == 1.0f) && (Mmat[5] == 0.0f) &&
        (Mmat[6] == 0.0f) && (Mmat[7] == 0.0f) && (Mmat[8] == 1.0f) &&
        (bx == 0.0f) && (by == 0.0f) && (bz == 0.0f);

    // ---- classify all 8 rays; row offsets -> SGPR, flags -> bitmasks ----
    unsigned fmask = 0u, imask = 0u;
    unsigned RO[RPW];
    #pragma unroll
    for (int i = 0; i < RPW; ++i) {
        const float sx = __shfl(sv, 3 * i + 0, 64);
        const float sy = __shfl(sv, 3 * i + 1, 64);
        const float sz = __shfl(sv, 3 * i + 2, 64);
        const float dxv = __fsub_rn(__shfl(dv, 3 * i + 0, 64), sx);
        const float dyv = __fsub_rn(__shfl(dv, 3 * i + 1, 64), sy);
        const float dzv = __fsub_rn(__shfl(dv, 3 * i + 2, 64), sz);
        const bool fr = fastM && (dxv == 0.0f) && (dyv == 0.0f) &&
                        isfinite(sx) && isfinite(sy) && isfinite(sz) &&
                        isfinite(dzv);
        const int ii = (int)rintf(sx);
        const int jj = (int)rintf(sy);
        const bool inb = ((unsigned)ii < NXV) && ((unsigned)jj < NYV);
        fmask |= (fr  ? 1u : 0u) << i;
        imask |= (inb ? 1u : 0u) << i;
        RO[i] = __builtin_amdgcn_readfirstlane(
            (fr && inb) ? ((unsigned)ii * NYV + (unsigned)jj) * NZV : 0u);
    }
    fmask = __builtin_amdgcn_readfirstlane(fmask);
    imask = __builtin_amdgcn_readfirstlane(imask);

    // ---- row prefetch: rays 0..2 ----
    const unsigned vo = 4u * (unsigned)lane;     // float offset within row
    f4vec rvv[RPW];
    #pragma unroll
    for (int i = 0; i < 3; ++i)
        rvv[i] = *reinterpret_cast<const f4vec*>(volume + RO[i] + vo);

    // de-interleaved LDS write: element e=4*lane+j -> slot j*64+lane
    #define WRITE_SLICE(s, r) do {                 \
        slice[s][0 * 64 + lane] = (r).x;           \
        slice[s][1 * 64 + lane] = (r).y;           \
        slice[s][2 * 64 + lane] = (r).z;           \
        slice[s][3 * 64 + lane] = (r).w;           \
    } while (0)

    WRITE_SLICE(0, rvv[0]);                        // ray 0 -> slice 0

    #pragma unroll
    for (int i = 0; i < RPW; ++i) {
        // pipeline maintenance (constant predicates under full unroll)
        if (i + 1 < RPW) WRITE_SLICE((i + 1) & 1, rvv[i + 1]);
        if (i + 3 < RPW)
            rvv[i + 3] = *reinterpret_cast<const f4vec*>(volume + RO[i + 3] + vo);
        if (i + 4 < RPW)
            tvv[i + 4] = __builtin_nontemporal_load(
                reinterpret_cast<const f4vec*>(tbase + (i + 4) * KPTS + 4 * lane));

        const int ray = ray0 + i;
        float acc = 0.0f;

        if ((fmask >> i) & 1u) {
            // ---------------- fast path ----------------
            if ((imask >> i) & 1u) {
                const float sz  = __shfl(sv, 3 * i + 2, 64);
                const float dzv = __fsub_rn(__shfl(dv, 3 * i + 2, 64), sz);
                const f4vec tv  = tvv[i];
                const float t4  = __shfl_down(tv.x, 1, 64);   // t[4(l+1)]
                const float* __restrict__ buf = slice[i & 1];

                const float p0 = __fadd_rn(sz, __fmul_rn(tv.x, dzv));
                const float p1 = __fadd_rn(sz, __fmul_rn(tv.y, dzv));
                const float p2 = __fadd_rn(sz, __fmul_rn(tv.z, dzv));
                const float p3 = __fadd_rn(sz, __fmul_rn(tv.w, dzv));
                const float p4 = __fadd_rn(sz, __fmul_rn(t4,   dzv));

                const bool f0 = !isinf(p0), f1 = !isinf(p1), f2 = !isinf(p2),
                           f3 = !isinf(p3), f4 = !isinf(p4);

                {   // seg 4l+0
                    const float ez   = __fsub_rn(p1, p0);
                    const float midz = __fmul_rn(0.5f, __fadd_rn(p0, p1));
                    const int   kk   = (int)rintf(midz);
                    const bool  v    = ((unsigned)kk < NZV) && f0 && f1;
                    const int   a    = ((kk & 3) << 6) + (kk >> 2);
                    acc = fmaf(buf[v ? a : 0], v ? fabsf(ez) : 0.0f, acc);
                }
                {   // seg 4l+1
                    const float ez   = __fsub_rn(p2, p1);
                    const float midz = __fmul_rn(0.5f, __fadd_rn(p1, p2));
                    const int   kk   = (int)rintf(midz);
                    const bool  v    = ((unsigned)kk < NZV) && f1 && f2;
                    const int   a    = ((kk & 3) << 6) + (kk >> 2);
                    acc = fmaf(buf[v ? a : 0], v ? fabsf(ez) : 0.0f, acc);
                }
                {   // seg 4l+2
                    const float ez   = __fsub_rn(p3, p2);
                    const float midz = __fmul_rn(0.5f, __fadd_rn(p2, p3));
                    const int   kk   = (int)rintf(midz);
                    const bool  v    = ((unsigned)kk < NZV) && f2 && f3;
                    const int   a    = ((kk & 3) << 6) + (kk >> 2);
                    acc = fmaf(buf[v ? a : 0], v ? fabsf(ez) : 0.0f, acc);
                }
                {   // seg 4l+3 (lane 63's is segment 255 -> masked)
                    const float ez   = __fsub_rn(p4, p3);
                    const float midz = __fmul_rn(0.5f, __fadd_rn(p3, p4));
                    const int   kk   = (int)rintf(midz);
                    const bool  v    = ((unsigned)kk < NZV) && f3 && f4 &&
                                       (lane != 63);
                    const int   a    = ((kk & 3) << 6) + (kk >> 2);
                    acc = fmaf(buf[v ? a : 0], v ? fabsf(ez) : 0.0f, acc);
                }
            }
            // else: whole ray OOB in x/y -> acc stays 0
        } else {
            // ------------- general path (reference-exact, rare) -------------
            const float sx = __shfl(sv, 3 * i + 0, 64);
            const float sy = __shfl(sv, 3 * i + 1, 64);
            const float sz = __shfl(sv, 3 * i + 2, 64);
            const float dxv = __fsub_rn(__shfl(dv, 3 * i + 0, 64), sx);
            const float dyv = __fsub_rn(__shfl(dv, 3 * i + 1, 64), sy);
            const float dzv = __fsub_rn(__shfl(dv, 3 * i + 2, 64), sz);

            const float m00 = Mmat[0], m01 = Mmat[1], m02 = Mmat[2];
            const float m10 = Mmat[3], m11 = Mmat[4], m12 = Mmat[5];
            const float m20 = Mmat[6], m21 = Mmat[7], m22 = Mmat[8];
            const float c00 =  (m11 * m22 - m12 * m21);
            const float c01 = -(m10 * m22 - m12 * m20);
            const float c02 =  (m10 * m21 - m11 * m20);
            const float det = m00 * c00 + m01 * c01 + m02 * c02;
            const float id  = 1.0f / det;
            const float i00 = c00 * id;
            const float i01 = -(m01 * m22 - m02 * m21) * id;
            const float i02 =  (m01 * m12 - m02 * m11) * id;
            const float i10 = c01 * id;
            const float i11 =  (m00 * m22 - m02 * m20) * id;
            const float i12 = -(m00 * m12 - m02 * m10) * id;
            const float i20 = c02 * id;
            const float i21 = -(m00 * m21 - m01 * m20) * id;
            const float i22 =  (m00 * m11 - m01 * m10) * id;

            const float* t = tbase + i * KPTS;
            #pragma unroll
            for (int it = 0; it < 4; ++it) {
                const int idx = it * 64 + lane;
                if (idx < KPTS - 1) {
                    const float tkv  = t[idx];
                    const float tk1v = t[idx + 1];
                    const float p0x = __fadd_rn(sx, __fmul_rn(tkv,  dxv));
                    const float p0y = __fadd_rn(sy, __fmul_rn(tkv,  dyv));
                    const float p0z = __fadd_rn(sz, __fmul_rn(tkv,  dzv));
                    const float p1x = __fadd_rn(sx, __fmul_rn(tk1v, dxv));
                    const float p1y = __fadd_rn(sy, __fmul_rn(tk1v, dyv));
                    const float p1z = __fadd_rn(sz, __fmul_rn(tk1v, dzv));

                    const bool infm = isinf(p0x) || isinf(p0y) || isinf(p0z) ||
                                      isinf(p1x) || isinf(p1y) || isinf(p1z);

                    const float ex = __fsub_rn(p1x, p0x);
                    const float ey = __fsub_rn(p1y, p0y);
                    const float ez = __fsub_rn(p1z, p0z);
                    const float seg = sqrtf(ex * ex + ey * ey + ez * ez);

                    const float mx = __fsub_rn(__fmul_rn(0.5f, __fadd_rn(p0x, p1x)), bx);
                    const float my = __fsub_rn(__fmul_rn(0.5f, __fadd_rn(p0y, p1y)), by);
                    const float mz = __fsub_rn(__fmul_rn(0.5f, __fadd_rn(p0z, p1z)), bz);

                    const float fi = __fadd_rn(__fadd_rn(__fmul_rn(i00, mx), __fmul_rn(i01, my)), __fmul_rn(i02, mz));
                    const float fj = __fadd_rn(__fadd_rn(__fmul_rn(i10, mx), __fmul_rn(i11, my)), __fmul_rn(i12, mz));
                    const float fk = __fadd_rn(__fadd_rn(__fmul_rn(i20, mx), __fmul_rn(i21, my)), __fmul_rn(i22, mz));

                    const int ii = (int)rintf(fi);
                    const int jj = (int)rintf(fj);
                    const int kk = (int)rintf(fk);

                    const bool oob = (ii < 0) || (ii >= NXV) ||
                                     (jj < 0) || (jj >= NYV) ||
                                     (kk < 0) || (kk >= NZV);

                    if (!infm && !oob) {
                        const float vox = volume[((size_t)ii * NYV + jj) * NZV + kk];
                        acc = fmaf(vox, seg, acc);
                    }
                }
            }
        }

        // 64-lane butterfly sum for ray i
        #pragma unroll
        for (int off = 32; off >= 1; off >>= 1)
            acc += __shfl_xor(acc, off, 64);

        if (lane == 0) out[ray] = acc;
    }
    #undef WRITE_SLICE
}

extern "C" void kernel_launch(void* const* d_in, const int* in_sizes, int n_in,
                              void* d_out, int out_size, void* d_ws, size_t ws_size,
                              hipStream_t stream) {
    const float* volume   = (const float*)d_in[0];
    const float* Mmat     = (const float*)d_in[1];
    const float* bvec     = (const float*)d_in[2];
    const float* src      = (const float*)d_in[3];
    const float* dst      = (const float*)d_in[4];
    const float* t_sorted = (const float*)d_in[5];
    float* out = (float*)d_out;

    // 8 rays/wave, 4 waves/block -> 32 rays/block
    const int grid = N_RAY / (RPW * 4);           // 2048 blocks
    ct_proj_kernel<<<grid, 256, 0, stream>>>(volume, Mmat, bvec, src, dst,
                                             t_sorted, out);
}

// Round 6
// 148.041 us; speedup vs baseline: 1.0374x; 1.0301x over previous
//
#include <hip/hip_runtime.h>
#include <math.h>

#define N_RAY 65536
#define KPTS 256
#define NXV 256
#define NYV 256
#define NZV 256
#define RPW 8   // rays per wave

typedef float f4vec __attribute__((ext_vector_type(4)));

// async global->LDS DMA: per-lane global src, wave-uniform LDS base;
// lane l receives bytes [16l, 16l+16) of the 1KB tile.
#define GLDS16(gsrc, ldst)                                                \
    __builtin_amdgcn_global_load_lds(                                     \
        (const __attribute__((address_space(1))) void*)(gsrc),            \
        (__attribute__((address_space(3))) void*)(ldst), 16, 0, 0)

#define WAITVM(n)  asm volatile("s_waitcnt vmcnt(" #n ")" ::: "memory")
#define WAITLGKM0  asm volatile("s_waitcnt lgkmcnt(0)" ::: "memory")

// 8 rays/wave. Both streams (t tile + volume row, 1KB each per ray) are
// staged via global_load_lds DMA into per-wave 4-slot LDS rings, prefetch
// distance 3, counted vmcnt waits (pair for ray i complete at vmcnt<=6
// while 3 newer pairs stay in flight). This moves all bulk reads off the
// VGPR-return/L1-MSHR path that capped R2-R5 at ~3.3 TB/s ingress.
//
// Fast-path math identical to R2-R5 (bit-exact vs reference: M==I bitwise,
// b==0, dx==dy==0 -> ii=rint(sx), jj=rint(sy), seg=|ez|; same per-lane fma
// order + 64-lane butterfly).
__global__ __launch_bounds__(256) void ct_proj_kernel(
    const float* __restrict__ volume,
    const float* __restrict__ Mmat,
    const float* __restrict__ bvec,
    const float* __restrict__ src,
    const float* __restrict__ dst,
    const float* __restrict__ t_sorted,
    float* __restrict__ out)
{
    __shared__ float tslot[4][4][KPTS];   // [wave][slot][256] = 16 KB
    __shared__ float rslot[4][4][NZV];    // 16 KB  (32 KB total -> 5 blk/CU)

    const int lane = threadIdx.x & 63;
    const int wid  = threadIdx.x >> 6;
    const int ray0 = (blockIdx.x * 4 + wid) * RPW;

    // ---- cooperative src/dst fetch (24 contiguous floats each) ----
    const int sdi = lane < 24 ? lane : 23;
    const float sv = src[3 * ray0 + sdi];
    const float dv = dst[3 * ray0 + sdi];

    const float bx = bvec[0], by = bvec[1], bz = bvec[2];
    const bool fastM =
        (Mmat[0] == 1.0f) && (Mmat[1] == 0.0f) && (Mmat[2] == 0.0f) &&
        (Mmat[3] == 0.0f) && (Mmat[4] == 1.0f) && (Mmat[5] == 0.0f) &&
        (Mmat[6] == 0.0f) && (Mmat[7] == 0.0f) && (Mmat[8] == 1.0f) &&
        (bx == 0.0f) && (by == 0.0f) && (bz == 0.0f);

    // ---- classify 8 rays; row offsets -> SGPRs, flags -> bitmasks ----
    unsigned fmask = 0u, imask = 0u;
    unsigned RO[RPW];
    #pragma unroll
    for (int i = 0; i < RPW; ++i) {
        const float sx = __shfl(sv, 3 * i + 0, 64);
        const float sy = __shfl(sv, 3 * i + 1, 64);
        const float sz = __shfl(sv, 3 * i + 2, 64);
        const float dxv = __fsub_rn(__shfl(dv, 3 * i + 0, 64), sx);
        const float dyv = __fsub_rn(__shfl(dv, 3 * i + 1, 64), sy);
        const float dzv = __fsub_rn(__shfl(dv, 3 * i + 2, 64), sz);
        const bool fr = fastM && (dxv == 0.0f) && (dyv == 0.0f) &&
                        isfinite(sx) && isfinite(sy) && isfinite(sz) &&
                        isfinite(dzv);
        const int ii = (int)rintf(sx);
        const int jj = (int)rintf(sy);
        const bool inb = ((unsigned)ii < NXV) && ((unsigned)jj < NYV);
        fmask |= (fr  ? 1u : 0u) << i;
        imask |= (inb ? 1u : 0u) << i;
        RO[i] = __builtin_amdgcn_readfirstlane(
            (fr && inb) ? ((unsigned)ii * NYV + (unsigned)jj) * NZV : 0u);
    }
    fmask = __builtin_amdgcn_readfirstlane(fmask);
    imask = __builtin_amdgcn_readfirstlane(imask);

    const float* tbase = t_sorted + (size_t)ray0 * KPTS;
    float rsel = 0.0f;   // lane r will end holding ray r's sum (fast path)

    if (fmask == 0xFFu) {
        // ================= DMA-pipelined fast path =================
        WAITVM(0);   // zero the vm counter (src/dst loads already consumed)

        #pragma unroll
        for (int i = 0; i < 3; ++i) {        // prologue: pairs 0..2 -> vm=6
            GLDS16(tbase + i * KPTS + 4 * lane, &tslot[wid][i][0]);
            GLDS16(volume + RO[i] + 4 * lane,   &rslot[wid][i][0]);
        }

        #pragma unroll
        for (int i = 0; i < RPW; ++i) {
            if (i < 5) {
                WAITLGKM0;   // prior slot's ds_reads done before DMA rewrite
                GLDS16(tbase + (i + 3) * KPTS + 4 * lane,
                       &tslot[wid][(i + 3) & 3][0]);
                GLDS16(volume + RO[i + 3] + 4 * lane,
                       &rslot[wid][(i + 3) & 3][0]);
            }
            // counted wait: ray i's pair is the oldest outstanding
            if (i <= 4)      { WAITVM(6); }
            else if (i == 5) { WAITVM(4); }
            else if (i == 6) { WAITVM(2); }
            else             { WAITVM(0); }

            const float* __restrict__ tb = &tslot[wid][i & 3][0];
            const float* __restrict__ rb = &rslot[wid][i & 3][0];

            const f4vec tv = *reinterpret_cast<const f4vec*>(tb + 4 * lane);
            const float t4 = __shfl_down(tv.x, 1, 64);   // t[4(l+1)]

            const float sz  = __shfl(sv, 3 * i + 2, 64);
            const float dzv = __fsub_rn(__shfl(dv, 3 * i + 2, 64), sz);
            const bool  inb = (imask >> i) & 1u;

            const float p0 = __fadd_rn(sz, __fmul_rn(tv.x, dzv));
            const float p1 = __fadd_rn(sz, __fmul_rn(tv.y, dzv));
            const float p2 = __fadd_rn(sz, __fmul_rn(tv.z, dzv));
            const float p3 = __fadd_rn(sz, __fmul_rn(tv.w, dzv));
            const float p4 = __fadd_rn(sz, __fmul_rn(t4,   dzv));

            const bool f0 = !isinf(p0), f1 = !isinf(p1), f2 = !isinf(p2),
                       f3 = !isinf(p3), f4 = !isinf(p4);

            float acc = 0.0f;
            {   // seg 4l+0
                const float ez   = __fsub_rn(p1, p0);
                const float midz = __fmul_rn(0.5f, __fadd_rn(p0, p1));
                const int   kk   = (int)rintf(midz);
                const bool  v    = ((unsigned)kk < NZV) && f0 && f1 && inb;
                acc = fmaf(rb[v ? kk : 0], v ? fabsf(ez) : 0.0f, acc);
            }
            {   // seg 4l+1
                const float ez   = __fsub_rn(p2, p1);
                const float midz = __fmul_rn(0.5f, __fadd_rn(p1, p2));
                const int   kk   = (int)rintf(midz);
                const bool  v    = ((unsigned)kk < NZV) && f1 && f2 && inb;
                acc = fmaf(rb[v ? kk : 0], v ? fabsf(ez) : 0.0f, acc);
            }
            {   // seg 4l+2
                const float ez   = __fsub_rn(p3, p2);
                const float midz = __fmul_rn(0.5f, __fadd_rn(p2, p3));
                const int   kk   = (int)rintf(midz);
                const bool  v    = ((unsigned)kk < NZV) && f2 && f3 && inb;
                acc = fmaf(rb[v ? kk : 0], v ? fabsf(ez) : 0.0f, acc);
            }
            {   // seg 4l+3 (lane 63's is segment 255 -> masked)
                const float ez   = __fsub_rn(p4, p3);
                const float midz = __fmul_rn(0.5f, __fadd_rn(p3, p4));
                const int   kk   = (int)rintf(midz);
                const bool  v    = ((unsigned)kk < NZV) && f3 && f4 && inb &&
                                   (lane != 63);
                acc = fmaf(rb[v ? kk : 0], v ? fabsf(ez) : 0.0f, acc);
            }

            // 64-lane butterfly (all lanes end with the sum)
            #pragma unroll
            for (int off = 32; off >= 1; off >>= 1)
                acc += __shfl_xor(acc, off, 64);

            rsel = (lane == i) ? acc : rsel;   // park ray i's sum in lane i
        }

        if (lane < RPW) out[ray0 + lane] = rsel;
    } else {
        // ============ general fallback (reference-exact, rare) ============
        const float m00 = Mmat[0], m01 = Mmat[1], m02 = Mmat[2];
        const float m10 = Mmat[3], m11 = Mmat[4], m12 = Mmat[5];
        const float m20 = Mmat[6], m21 = Mmat[7], m22 = Mmat[8];
        const float c00 =  (m11 * m22 - m12 * m21);
        const float c01 = -(m10 * m22 - m12 * m20);
        const float c02 =  (m10 * m21 - m11 * m20);
        const float det = m00 * c00 + m01 * c01 + m02 * c02;
        const float id  = 1.0f / det;
        const float i00 = c00 * id;
        const float i01 = -(m01 * m22 - m02 * m21) * id;
        const float i02 =  (m01 * m12 - m02 * m11) * id;
        const float i10 = c01 * id;
        const float i11 =  (m00 * m22 - m02 * m20) * id;
        const float i12 = -(m00 * m12 - m02 * m10) * id;
        const float i20 = c02 * id;
        const float i21 = -(m00 * m21 - m01 * m20) * id;
        const float i22 =  (m00 * m11 - m01 * m10) * id;

        for (int i = 0; i < RPW; ++i) {
            const float sx = __shfl(sv, 3 * i + 0, 64);
            const float sy = __shfl(sv, 3 * i + 1, 64);
            const float sz = __shfl(sv, 3 * i + 2, 64);
            const float dxv = __fsub_rn(__shfl(dv, 3 * i + 0, 64), sx);
            const float dyv = __fsub_rn(__shfl(dv, 3 * i + 1, 64), sy);
            const float dzv = __fsub_rn(__shfl(dv, 3 * i + 2, 64), sz);

            const float* t = tbase + i * KPTS;
            float acc = 0.0f;
            #pragma unroll
            for (int it = 0; it < 4; ++it) {
                const int idx = it * 64 + lane;
                if (idx < KPTS - 1) {
                    const float tkv  = t[idx];
                    const float tk1v = t[idx + 1];
                    const float p0x = __fadd_rn(sx, __fmul_rn(tkv,  dxv));
                    const float p0y = __fadd_rn(sy, __fmul_rn(tkv,  dyv));
                    const float p0z = __fadd_rn(sz, __fmul_rn(tkv,  dzv));
                    const float p1x = __fadd_rn(sx, __fmul_rn(tk1v, dxv));
                    const float p1y = __fadd_rn(sy, __fmul_rn(tk1v, dyv));
                    const float p1z = __fadd_rn(sz, __fmul_rn(tk1v, dzv));

                    const bool infm = isinf(p0x) || isinf(p0y) || isinf(p0z) ||
                                      isinf(p1x) || isinf(p1y) || isinf(p1z);

                    const float ex = __fsub_rn(p1x, p0x);
                    const float ey = __fsub_rn(p1y, p0y);
                    const float ez = __fsub_rn(p1z, p0z);
                    const float seg = sqrtf(ex * ex + ey * ey + ez * ez);

                    const float mx = __fsub_rn(__fmul_rn(0.5f, __fadd_rn(p0x, p1x)), bx);
                    const float my = __fsub_rn(__fmul_rn(0.5f, __fadd_rn(p0y, p1y)), by);
                    const float mz = __fsub_rn(__fmul_rn(0.5f, __fadd_rn(p0z, p1z)), bz);

                    const float fi = __fadd_rn(__fadd_rn(__fmul_rn(i00, mx), __fmul_rn(i01, my)), __fmul_rn(i02, mz));
                    const float fj = __fadd_rn(__fadd_rn(__fmul_rn(i10, mx), __fmul_rn(i11, my)), __fmul_rn(i12, mz));
                    const float fk = __fadd_rn(__fadd_rn(__fmul_rn(i20, mx), __fmul_rn(i21, my)), __fmul_rn(i22, mz));

                    const int ii = (int)rintf(fi);
                    const int jj = (int)rintf(fj);
                    const int kk = (int)rintf(fk);

                    const bool oob = (ii < 0) || (ii >= NXV) ||
                                     (jj < 0) || (jj >= NYV) ||
                                     (kk < 0) || (kk >= NZV);

                    if (!infm && !oob) {
                        const float vox = volume[((size_t)ii * NYV + jj) * NZV + kk];
                        acc = fmaf(vox, seg, acc);
                    }
                }
            }
            #pragma unroll
            for (int off = 32; off >= 1; off >>= 1)
                acc += __shfl_xor(acc, off, 64);
            if (lane == 0) out[ray0 + i] = acc;
        }
    }
}

extern "C" void kernel_launch(void* const* d_in, const int* in_sizes, int n_in,
                              void* d_out, int out_size, void* d_ws, size_t ws_size,
                              hipStream_t stream) {
    const float* volume   = (const float*)d_in[0];
    const float* Mmat     = (const float*)d_in[1];
    const float* bvec     = (const float*)d_in[2];
    const float* src      = (const float*)d_in[3];
    const float* dst      = (const float*)d_in[4];
    const float* t_sorted = (const float*)d_in[5];
    float* out = (float*)d_out;

    const int grid = N_RAY / (RPW * 4);           // 2048 blocks x 32 rays
    ct_proj_kernel<<<grid, 256, 0, stream>>>(volume, Mmat, bvec, src, dst,
                                             t_sorted, out);
}